// Round 1
// baseline (10.398 us; speedup 1.0000x reference)
//
#include <hip/hip_runtime.h>
#include <math.h>

// L0-gated SINDy polynomial regression, eval-mode.
// out[b] = sum_j polyfeat(x_b)[j] * z[j] * w[j],
//   z = clip(sigmoid(qz)*1.2 - 0.1, 0, 1)
// x_b = [obs[b,0..2], act[b]]; 35 monomials of degree <= 3 over 4 vars,
// sklearn PolynomialFeatures ordering (bias, deg1, deg2 cwr, deg3 cwr).

#define NCOEF 35

__global__ __launch_bounds__(256) void l0sindy_kernel(
    const float* __restrict__ obs,   // [B,3]
    const float* __restrict__ act,   // [B,1]
    const float* __restrict__ w,     // [35,1]
    const float* __restrict__ qz,    // [35]
    float* __restrict__ out,         // [B,1]
    int nquads)                      // B/4
{
    __shared__ float c[NCOEF];
    const int tid = threadIdx.x;
    if (tid < NCOEF) {
        float q = qz[tid];
        float s = 1.0f / (1.0f + expf(-q));
        float z = fmaf(s, 1.2f, -0.1f);           // sigmoid*(zeta-gamma)+gamma
        z = fminf(fmaxf(z, 0.0f), 1.0f);
        c[tid] = z * w[tid];
    }
    __syncthreads();

    const int t = blockIdx.x * blockDim.x + tid;  // quad index: rows 4t..4t+3
    if (t >= nquads) return;

    const float4* obs4 = reinterpret_cast<const float4*>(obs);
    const float4  o0 = obs4[3 * t + 0];
    const float4  o1 = obs4[3 * t + 1];
    const float4  o2 = obs4[3 * t + 2];
    const float4  a  = reinterpret_cast<const float4*>(act)[t];

    // de-interleave 4 rows of [x0,x1,x2] + act
    const float xr[4][4] = {
        { o0.x, o0.y, o0.z, a.x },
        { o0.w, o1.x, o1.y, a.y },
        { o1.z, o1.w, o2.x, a.z },
        { o2.y, o2.z, o2.w, a.w },
    };

    float4 res;
    float* resp = reinterpret_cast<float*>(&res);

    #pragma unroll
    for (int r = 0; r < 4; ++r) {
        const float x0 = xr[r][0], x1 = xr[r][1], x2 = xr[r][2], x3 = xr[r][3];

        // degree-2 products (reused for degree 3)
        const float x00 = x0 * x0, x01 = x0 * x1, x02 = x0 * x2, x03 = x0 * x3;
        const float x11 = x1 * x1, x12 = x1 * x2, x13 = x1 * x3;
        const float x22 = x2 * x2, x23 = x2 * x3, x33 = x3 * x3;

        float acc = c[0];
        // degree 1
        acc = fmaf(c[1],  x0,  acc);
        acc = fmaf(c[2],  x1,  acc);
        acc = fmaf(c[3],  x2,  acc);
        acc = fmaf(c[4],  x3,  acc);
        // degree 2: (0,0)(0,1)(0,2)(0,3)(1,1)(1,2)(1,3)(2,2)(2,3)(3,3)
        acc = fmaf(c[5],  x00, acc);
        acc = fmaf(c[6],  x01, acc);
        acc = fmaf(c[7],  x02, acc);
        acc = fmaf(c[8],  x03, acc);
        acc = fmaf(c[9],  x11, acc);
        acc = fmaf(c[10], x12, acc);
        acc = fmaf(c[11], x13, acc);
        acc = fmaf(c[12], x22, acc);
        acc = fmaf(c[13], x23, acc);
        acc = fmaf(c[14], x33, acc);
        // degree 3: cwr over 4 vars
        acc = fmaf(c[15], x00 * x0, acc);  // (0,0,0)
        acc = fmaf(c[16], x00 * x1, acc);  // (0,0,1)
        acc = fmaf(c[17], x00 * x2, acc);  // (0,0,2)
        acc = fmaf(c[18], x00 * x3, acc);  // (0,0,3)
        acc = fmaf(c[19], x01 * x1, acc);  // (0,1,1)
        acc = fmaf(c[20], x01 * x2, acc);  // (0,1,2)
        acc = fmaf(c[21], x01 * x3, acc);  // (0,1,3)
        acc = fmaf(c[22], x02 * x2, acc);  // (0,2,2)
        acc = fmaf(c[23], x02 * x3, acc);  // (0,2,3)
        acc = fmaf(c[24], x03 * x3, acc);  // (0,3,3)
        acc = fmaf(c[25], x11 * x1, acc);  // (1,1,1)
        acc = fmaf(c[26], x11 * x2, acc);  // (1,1,2)
        acc = fmaf(c[27], x11 * x3, acc);  // (1,1,3)
        acc = fmaf(c[28], x12 * x2, acc);  // (1,2,2)
        acc = fmaf(c[29], x12 * x3, acc);  // (1,2,3)
        acc = fmaf(c[30], x13 * x3, acc);  // (1,3,3)
        acc = fmaf(c[31], x22 * x2, acc);  // (2,2,2)
        acc = fmaf(c[32], x22 * x3, acc);  // (2,2,3)
        acc = fmaf(c[33], x23 * x3, acc);  // (2,3,3)
        acc = fmaf(c[34], x33 * x3, acc);  // (3,3,3)

        resp[r] = acc;
    }

    reinterpret_cast<float4*>(out)[t] = res;
}

extern "C" void kernel_launch(void* const* d_in, const int* in_sizes, int n_in,
                              void* d_out, int out_size, void* d_ws, size_t ws_size,
                              hipStream_t stream) {
    const float* obs = (const float*)d_in[0];   // [B,3]
    const float* act = (const float*)d_in[1];   // [B,1]
    const float* w   = (const float*)d_in[2];   // [35,1]
    const float* qz  = (const float*)d_in[3];   // [35]
    float* out = (float*)d_out;

    const int B = in_sizes[0] / 3;              // 1048576
    const int nquads = B / 4;                   // B is 2^20, divisible by 4
    const int block = 256;
    const int grid = (nquads + block - 1) / block;

    l0sindy_kernel<<<grid, block, 0, stream>>>(obs, act, w, qz, out, nquads);
}